// Round 5
// baseline (384.878 us; speedup 1.0000x reference)
//
#include <hip/hip_runtime.h>
#include <cstddef>
#include <math.h>

#define L_DIM 2048
#define C_DIM 512
#define CQ_DIM 64
#define B_DIM 8

typedef _Float16 f16x8 __attribute__((ext_vector_type(8)));
typedef __fp16 fp16x2_t __attribute__((ext_vector_type(2)));
typedef float f32x4 __attribute__((ext_vector_type(4)));

__device__ __forceinline__ unsigned short f2h(float f) {
    union { _Float16 h; unsigned short u; } v;
    v.h = (_Float16)f;
    return v.u;
}

// packed fp32x2 -> fp16x2 (RTZ) as uint
__device__ __forceinline__ unsigned p2u(float a, float b) {
    union { fp16x2_t h; unsigned u; } v;
    v.h = __builtin_amdgcn_cvt_pkrtz(a, b);
    return v.u;
}

// ---------------------------------------------------------------------------
// prep_w: Wq/Wk/Wv (fp32 [co][ci][3]) -> Wh fp16 [t][640co][512ci]
// ---------------------------------------------------------------------------
__global__ __launch_bounds__(256) void prep_w(const float* __restrict__ Wq,
                                              const float* __restrict__ Wk,
                                              const float* __restrict__ Wv,
                                              unsigned short* __restrict__ Wh) {
    const int idx = blockIdx.x * 256 + threadIdx.x;
    const int ci = idx & 511;
    const int co = (idx >> 9) % 640;
    const int t  = idx / (640 * 512);
    float w;
    if (co < 64)       w = Wq[(size_t)co * 1536 + ci * 3 + t];
    else if (co < 128) w = Wk[(size_t)(co - 64) * 1536 + ci * 3 + t];
    else               w = Wv[(size_t)(co - 128) * 1536 + ci * 3 + t];
    Wh[idx] = f2h(w);
}

// ---------------------------------------------------------------------------
// prep_x: x fp32 [b][ci][l] -> xT fp16 [b][l][512ci]. 64ci x 64l tile per block.
// ---------------------------------------------------------------------------
__global__ __launch_bounds__(256) void prep_x(const float* __restrict__ x,
                                              unsigned short* __restrict__ xT) {
    const int l0  = blockIdx.x * 64;
    const int ci0 = blockIdx.y * 64;
    const int b   = blockIdx.z;

    __shared__ float xs[64][68];
    const int tid = threadIdx.x;
    const float* xb = x + ((size_t)b * C_DIM + ci0) * L_DIM;

    for (int idx = tid; idx < 64 * 16; idx += 256) {
        int ci = idx >> 4, lq = idx & 15;
        *(float4*)&xs[ci][lq * 4] = *(const float4*)&xb[(size_t)ci * L_DIM + l0 + lq * 4];
    }
    __syncthreads();

    unsigned short* ob = xT + ((size_t)b * L_DIM + l0) * C_DIM + ci0;
    for (int idx = tid; idx < 64 * 8; idx += 256) {
        int l = idx >> 3, c8 = idx & 7;
        ushort4 r0, r1;
        r0.x = f2h(xs[c8 * 8 + 0][l]); r0.y = f2h(xs[c8 * 8 + 1][l]);
        r0.z = f2h(xs[c8 * 8 + 2][l]); r0.w = f2h(xs[c8 * 8 + 3][l]);
        r1.x = f2h(xs[c8 * 8 + 4][l]); r1.y = f2h(xs[c8 * 8 + 5][l]);
        r1.z = f2h(xs[c8 * 8 + 6][l]); r1.w = f2h(xs[c8 * 8 + 7][l]);
        *(ushort4*)&ob[(size_t)l * C_DIM + c8 * 8] = r0;
        *(ushort4*)&ob[(size_t)l * C_DIM + c8 * 8 + 4] = r1;
    }
}

// ---------------------------------------------------------------------------
// conv_all: out[co,l] = sum_t sum_ci Wh[t][co][ci] * x[ci][l+t-1] via MFMA.
// ---------------------------------------------------------------------------
__global__ __launch_bounds__(256) void conv_all(const unsigned short* __restrict__ Wh,
                                                const unsigned short* __restrict__ xT,
                                                unsigned short* __restrict__ qT,
                                                unsigned short* __restrict__ kT,
                                                unsigned short* __restrict__ vB) {
    const int l0  = blockIdx.x * 128;
    const int co0 = blockIdx.y * 64;
    const int b   = blockIdx.z;

    __shared__ unsigned short As[3][64][40];
    __shared__ unsigned short Bs[130][40];

    const int tid  = threadIdx.x;
    const int lane = tid & 63, w = tid >> 6;
    const int ln15 = lane & 15, quad = lane >> 4;

    const int co_w = (w & 1) * 32;
    const int l_w  = (w >> 1) * 64;

    const unsigned short* xb = xT + (size_t)b * L_DIM * C_DIM;

    f32x4 acc[2][4] = {};

    for (int ci0 = 0; ci0 < C_DIM; ci0 += 32) {
        __syncthreads();
        for (int idx = tid; idx < 768; idx += 256) {
            int t = idx >> 8, co = (idx >> 2) & 63, c8 = idx & 3;
            *(float4*)&As[t][co][c8 * 8] =
                *(const float4*)&Wh[(((size_t)t * 640) + co0 + co) * C_DIM + ci0 + c8 * 8];
        }
        for (int idx = tid; idx < 520; idx += 256) {
            int la = idx >> 2, c8 = idx & 3;
            int l = l0 - 1 + la;
            float4 vx = {0.f, 0.f, 0.f, 0.f};
            if (l >= 0 && l < L_DIM)
                vx = *(const float4*)&xb[(size_t)l * C_DIM + ci0 + c8 * 8];
            *(float4*)&Bs[la][c8 * 8] = vx;
        }
        __syncthreads();

#pragma unroll
        for (int t = 0; t < 3; t++) {
            f16x8 a[2], bfr[4];
#pragma unroll
            for (int ct = 0; ct < 2; ct++)
                a[ct] = *(const f16x8*)&As[t][co_w + ct * 16 + ln15][quad * 8];
#pragma unroll
            for (int lt = 0; lt < 4; lt++)
                bfr[lt] = *(const f16x8*)&Bs[l_w + lt * 16 + ln15 + t][quad * 8];
#pragma unroll
            for (int ct = 0; ct < 2; ct++)
#pragma unroll
                for (int lt = 0; lt < 4; lt++)
                    acc[ct][lt] = __builtin_amdgcn_mfma_f32_16x16x32_f16(a[ct], bfr[lt], acc[ct][lt], 0, 0, 0);
        }
    }

    if (co0 < 128) {
        unsigned short* dst = (co0 == 0 ? qT : kT) + (size_t)b * L_DIM * CQ_DIM;
#pragma unroll
        for (int ct = 0; ct < 2; ct++)
#pragma unroll
            for (int lt = 0; lt < 4; lt++) {
                const int l = l0 + l_w + lt * 16 + ln15;
                ushort4 r;
                r.x = f2h(acc[ct][lt][0]); r.y = f2h(acc[ct][lt][1]);
                r.z = f2h(acc[ct][lt][2]); r.w = f2h(acc[ct][lt][3]);
                *(ushort4*)&dst[(size_t)l * CQ_DIM + co_w + ct * 16 + quad * 4] = r;
            }
    } else {
        unsigned short* dst = vB + ((size_t)b * C_DIM + (co0 - 128)) * L_DIM;
#pragma unroll
        for (int ct = 0; ct < 2; ct++)
#pragma unroll
            for (int lt = 0; lt < 4; lt++) {
                const int l = l0 + l_w + lt * 16 + ln15;
#pragma unroll
                for (int r = 0; r < 4; r++) {
                    const int co = co_w + ct * 16 + quad * 4 + r;
                    dst[(size_t)co * L_DIM + l] = f2h(acc[ct][lt][r]);
                }
            }
    }
}

// ---------------------------------------------------------------------------
// stat_k: per-j softmax stats over an i-chunk of 256. Grid (8 ich, 32 jb, 8 b)
// = 2048 blocks (8/CU). Writes partial (m, l) to pstat:
//   pm[(ich*8 + b)*2048 + j], pl at +8*8*2048 floats.
// ---------------------------------------------------------------------------
__global__ __launch_bounds__(256) void stat_k(const unsigned short* __restrict__ qT,
                                              const unsigned short* __restrict__ kT,
                                              float* __restrict__ pstat) {
    const int ich = blockIdx.x;
    const int j0  = blockIdx.y * 64;
    const int b   = blockIdx.z;

    __shared__ unsigned short sbuf[64 * 68];

    const int tid = threadIdx.x;
    const int lane = tid & 63, w = tid >> 6;
    const int ln15 = lane & 15, quad = lane >> 4;
    const int sj = w * 16;

    const unsigned short* qb = qT + (size_t)b * L_DIM * CQ_DIM;
    const unsigned short* kb = kT + (size_t)b * L_DIM * CQ_DIM;

    // stage kT j-block, hoist K-fragments
    for (int idx = tid; idx < 64 * 8; idx += 256) {
        int r = idx >> 3, c8 = idx & 7;
        *(float4*)&sbuf[r * 68 + c8 * 8] = *(const float4*)&kb[(size_t)(j0 + r) * CQ_DIM + c8 * 8];
    }
    __syncthreads();
    f16x8 kfr[2];
#pragma unroll
    for (int cc = 0; cc < 2; cc++)
        kfr[cc] = *(const f16x8*)&sbuf[(sj + ln15) * 68 + cc * 32 + quad * 8];

    float m_run = -1e30f, l_run = 0.f;

    for (int t = 0; t < 4; t++) {
        const int i0 = ich * 256 + t * 64;
        __syncthreads();   // orders kfr / prior-iter sbuf reads before overwrite
        for (int idx = tid; idx < 64 * 8; idx += 256) {
            int r = idx >> 3, c8 = idx & 7;
            *(float4*)&sbuf[r * 68 + c8 * 8] = *(const float4*)&qb[(size_t)(i0 + r) * CQ_DIM + c8 * 8];
        }
        __syncthreads();

        f32x4 sacc[4] = {};
#pragma unroll
        for (int cc = 0; cc < 2; cc++) {
#pragma unroll
            for (int it = 0; it < 4; it++) {
                const f16x8 afr = *(const f16x8*)&sbuf[(it * 16 + ln15) * 68 + cc * 32 + quad * 8];
                sacc[it] = __builtin_amdgcn_mfma_f32_16x16x32_f16(afr, kfr[cc], sacc[it], 0, 0, 0);
            }
        }

        float bm = -1e30f;
#pragma unroll
        for (int it = 0; it < 4; it++)
#pragma unroll
            for (int r = 0; r < 4; r++)
                bm = fmaxf(bm, sacc[it][r]);
        bm = fmaxf(bm, __shfl_xor(bm, 16, 64));
        bm = fmaxf(bm, __shfl_xor(bm, 32, 64));
        const float m_new = fmaxf(m_run, bm);
        const float alpha = __expf(m_run - m_new);

        float lsum = 0.f;
#pragma unroll
        for (int it = 0; it < 4; it++) {
            float p0 = __expf(sacc[it][0] - m_new);
            float p1 = __expf(sacc[it][1] - m_new);
            float p2 = __expf(sacc[it][2] - m_new);
            float p3 = __expf(sacc[it][3] - m_new);
            lsum += (p0 + p1) + (p2 + p3);
        }
        lsum += __shfl_xor(lsum, 16, 64);
        lsum += __shfl_xor(lsum, 32, 64);
        l_run = l_run * alpha + lsum;
        m_run = m_new;
    }

    if (quad == 0) {
        const int j = j0 + sj + ln15;
        float* pm = pstat;
        float* pl = pstat + 8 * 8 * 2048;
        pm[((size_t)ich * 8 + b) * 2048 + j] = m_run;
        pl[((size_t)ich * 8 + b) * 2048 + j] = l_run;
    }
}

// ---------------------------------------------------------------------------
// pv2: dependency-free PV pass using precomputed exact (m_j, l_j).
// Block tile 64j x 128co (4 waves), grid (32, 4, 8) = 1024 blocks, ~35 KB LDS.
// Wave-owned-j: wave w handles j-group w*16 END-TO-END (scores S[64i x 16j],
// p = exp(S - m_j), P rows, AND O[128co x 16j]). P never crosses waves ->
// only 2 barriers/iter (around the shared qTs/vvs stage), and after barrier 2
// each wave's score->exp->PV chain runs decoupled (phase skew across waves
// hides VALU under MFMA; setprio arbitrates).
// T14: next i-tile q/V prefetched into registers right after barrier 2;
// LDS writes happen at the top of the next iteration (latency hidden under
// score+exp+PV). VGPR headroom confirmed: round-4 was 56.
// ---------------------------------------------------------------------------
__global__ __launch_bounds__(256) void pv2(const unsigned short* __restrict__ qT,
                                           const unsigned short* __restrict__ kT,
                                           const unsigned short* __restrict__ vB,
                                           const float* __restrict__ pstat,
                                           const float* __restrict__ gamma,
                                           float* __restrict__ out) {
    const int j0  = blockIdx.x * 64;
    const int co0 = blockIdx.y * 128;
    const int b   = blockIdx.z;

    __shared__ unsigned short pps[64 * 68];   // init: kT stage [j][c]; loop: p [j][i] (wave-private rows)
    __shared__ unsigned short qTs[64 * 68];   // [i][c]
    __shared__ unsigned short vvs[128 * 68];  // [co][i]
    __shared__ float mj_s[64];
    __shared__ float il_s[64];

    const int tid = threadIdx.x;
    const int lane = tid & 63, w = tid >> 6;
    const int ln15 = lane & 15, quad = lane >> 4;

    const unsigned short* qb = qT + (size_t)b * L_DIM * CQ_DIM;
    const unsigned short* kb = kT + (size_t)b * L_DIM * CQ_DIM;
    const unsigned short* vb = vB + (size_t)b * C_DIM * L_DIM;

    const int sj = w * 16;   // wave's j group (owned end-to-end)

    // ---- merge per-chunk stats for this block's 64 j ----
    if (tid < 64) {
        const int j = j0 + tid;
        const float* pm = pstat;
        const float* pl = pstat + 8 * 8 * 2048;
        float m = -1e30f;
        float pmv[8];
#pragma unroll
        for (int c = 0; c < 8; c++) {
            pmv[c] = pm[((size_t)c * 8 + b) * 2048 + j];
            m = fmaxf(m, pmv[c]);
        }
        float l = 0.f;
#pragma unroll
        for (int c = 0; c < 8; c++)
            l = fmaf(pl[((size_t)c * 8 + b) * 2048 + j], __expf(pmv[c] - m), l);
        mj_s[tid] = m;
        il_s[tid] = gamma[0] / l;
    }

    // ---- stage kT once, hoist this wave's K-fragments (8 VGPRs) ----
    for (int idx = tid; idx < 64 * 8; idx += 256) {
        int r = idx >> 3, c8 = idx & 7;
        *(float4*)&pps[r * 68 + c8 * 8] = *(const float4*)&kb[(size_t)(j0 + r) * CQ_DIM + c8 * 8];
    }
    __syncthreads();
    f16x8 kfr[2];
#pragma unroll
    for (int cc = 0; cc < 2; cc++)
        kfr[cc] = *(const f16x8*)&pps[(sj + ln15) * 68 + cc * 32 + quad * 8];
    const float m_lane   = mj_s[sj + ln15];   // this lane's j max
    const float inv_lane = il_s[sj + ln15];   // gamma / l_j

    f32x4 oacc[8] = {};   // O[co-tile a][j = sj+ln15 col], a = 0..7 covers 128 co

    // ---- T14 prologue: prefetch first q/V tiles into registers ----
    const int sr = tid >> 3;          // staging row (+32k)
    const int sc = (tid & 7) * 8;     // 16B column chunk
    float4 rq[2], rv[4];
    rq[0] = *(const float4*)&qb[(size_t)sr * CQ_DIM + sc];
    rq[1] = *(const float4*)&qb[(size_t)(sr + 32) * CQ_DIM + sc];
#pragma unroll
    for (int k = 0; k < 4; k++)
        rv[k] = *(const float4*)&vb[(size_t)(co0 + sr + 32 * k) * L_DIM + sc];

    for (int i0 = 0; i0 < L_DIM; i0 += 64) {
        __syncthreads();   // all waves done reading qTs/vvs of prior iter
        *(float4*)&qTs[sr * 68 + sc] = rq[0];
        *(float4*)&qTs[(sr + 32) * 68 + sc] = rq[1];
#pragma unroll
        for (int k = 0; k < 4; k++)
            *(float4*)&vvs[(sr + 32 * k) * 68 + sc] = rv[k];
        __syncthreads();

        // T14: issue next-iter global loads; latency hides under score+exp+PV
        if (i0 + 64 < L_DIM) {
            const int i1 = i0 + 64;
            rq[0] = *(const float4*)&qb[(size_t)(i1 + sr) * CQ_DIM + sc];
            rq[1] = *(const float4*)&qb[(size_t)(i1 + sr + 32) * CQ_DIM + sc];
#pragma unroll
            for (int k = 0; k < 4; k++)
                rv[k] = *(const float4*)&vb[(size_t)(co0 + sr + 32 * k) * L_DIM + i1 + sc];
        }

        // scores: S[64i x 16j] for this wave's j group
        f32x4 sacc[4] = {};
        __builtin_amdgcn_s_setprio(1);
#pragma unroll
        for (int cc = 0; cc < 2; cc++) {
#pragma unroll
            for (int it = 0; it < 4; it++) {
                const f16x8 afr = *(const f16x8*)&qTs[(it * 16 + ln15) * 68 + cc * 32 + quad * 8];
                sacc[it] = __builtin_amdgcn_mfma_f32_16x16x32_f16(afr, kfr[cc], sacc[it], 0, 0, 0);
            }
        }
        __builtin_amdgcn_s_setprio(0);

        // p = exp(S - m_j), written to this wave's own pps rows
        const int j = sj + ln15;
#pragma unroll
        for (int it = 0; it < 4; it++) {
            float p0 = __expf(sacc[it][0] - m_lane);
            float p1 = __expf(sacc[it][1] - m_lane);
            float p2 = __expf(sacc[it][2] - m_lane);
            float p3 = __expf(sacc[it][3] - m_lane);
            uint2 u;
            u.x = p2u(p0, p1);
            u.y = p2u(p2, p3);
            *(uint2*)&pps[j * 68 + it * 16 + quad * 4] = u;
        }
        // no barrier: this wave reads back only its own rows (lgkmcnt orders)

        // PV: oacc[a] += V[128co x 64i] * P[64i x 16j(own)]
        __builtin_amdgcn_s_setprio(1);
#pragma unroll
        for (int ks = 0; ks < 2; ks++) {
            const f16x8 bfr = *(const f16x8*)&pps[(sj + ln15) * 68 + ks * 32 + quad * 8];
#pragma unroll
            for (int a = 0; a < 8; a++) {
                const f16x8 afr = *(const f16x8*)&vvs[(a * 16 + ln15) * 68 + ks * 32 + quad * 8];
                oacc[a] = __builtin_amdgcn_mfma_f32_16x16x32_f16(afr, bfr, oacc[a], 0, 0, 0);
            }
        }
        __builtin_amdgcn_s_setprio(0);
    }

    // epilogue: out = oacc * (gamma / l_j), col j = j0 + sj + ln15
#pragma unroll
    for (int a = 0; a < 8; a++)
#pragma unroll
        for (int r = 0; r < 4; r++) {
            const int co = co0 + a * 16 + quad * 4 + r;
            out[((size_t)b * C_DIM + co) * L_DIM + j0 + sj + ln15] = oacc[a][r] * inv_lane;
        }
}

// ---------------------------------------------------------------------------
extern "C" void kernel_launch(void* const* d_in, const int* in_sizes, int n_in,
                              void* d_out, int out_size, void* d_ws, size_t ws_size,
                              hipStream_t stream) {
    const float* x     = (const float*)d_in[0];
    const float* Wq    = (const float*)d_in[1];
    const float* Wk    = (const float*)d_in[2];
    const float* Wv    = (const float*)d_in[3];
    const float* gamma = (const float*)d_in[4];
    float* out = (float*)d_out;

    unsigned short* ws_h = (unsigned short*)d_ws;
    unsigned short* qT = ws_h;                        // 8*2048*64   = 1,048,576
    unsigned short* kT = qT + 1048576;
    unsigned short* vB = kT + 1048576;                // 8*512*2048  = 8,388,608
    unsigned short* xT = vB + 8388608;                // 8*2048*512  = 8,388,608
    unsigned short* Wh = xT + 8388608;                // 3*640*512   = 983,040
    // stats reuse the xT region (dead after conv_all): 2 * 8*8*2048 floats = 1 MB
    float* pstat = (float*)xT;

    prep_w  <<<3840, 256, 0, stream>>>(Wq, Wk, Wv, Wh);
    prep_x  <<<dim3(32, 8, 8), 256, 0, stream>>>(x, xT);
    conv_all<<<dim3(16, 10, 8), 256, 0, stream>>>(Wh, xT, qT, kT, vB);
    stat_k  <<<dim3(8, 32, 8), 256, 0, stream>>>(qT, kT, pstat);
    pv2     <<<dim3(32, 4, 8), 256, 0, stream>>>(qT, kT, vB, pstat, gamma, out);
}

// Round 6
// 289.743 us; speedup vs baseline: 1.3283x; 1.3283x over previous
//
#include <hip/hip_runtime.h>
#include <cstddef>
#include <math.h>

#define L_DIM 2048
#define C_DIM 512
#define CQ_DIM 64
#define B_DIM 8
#define LOG2E 1.44269504088896340736f

typedef _Float16 f16x8 __attribute__((ext_vector_type(8)));
typedef __fp16 fp16x2_t __attribute__((ext_vector_type(2)));
typedef float f32x4 __attribute__((ext_vector_type(4)));

__device__ __forceinline__ unsigned short f2h(float f) {
    union { _Float16 h; unsigned short u; } v;
    v.h = (_Float16)f;
    return v.u;
}

// packed fp32x2 -> fp16x2 (RTZ) as uint
__device__ __forceinline__ unsigned p2u(float a, float b) {
    union { fp16x2_t h; unsigned u; } v;
    v.h = __builtin_amdgcn_cvt_pkrtz(a, b);
    return v.u;
}

// ---------------------------------------------------------------------------
// prep_w: Wq/Wk/Wv (fp32 [co][ci][3]) -> Wh fp16 [t][640co][512ci]
// ---------------------------------------------------------------------------
__global__ __launch_bounds__(256) void prep_w(const float* __restrict__ Wq,
                                              const float* __restrict__ Wk,
                                              const float* __restrict__ Wv,
                                              unsigned short* __restrict__ Wh) {
    const int idx = blockIdx.x * 256 + threadIdx.x;
    const int ci = idx & 511;
    const int co = (idx >> 9) % 640;
    const int t  = idx / (640 * 512);
    float w;
    if (co < 64)       w = Wq[(size_t)co * 1536 + ci * 3 + t];
    else if (co < 128) w = Wk[(size_t)(co - 64) * 1536 + ci * 3 + t];
    else               w = Wv[(size_t)(co - 128) * 1536 + ci * 3 + t];
    Wh[idx] = f2h(w);
}

// ---------------------------------------------------------------------------
// prep_x: x fp32 [b][ci][l] -> xT fp16 [b][l][512ci]. 64ci x 64l tile per block.
// ---------------------------------------------------------------------------
__global__ __launch_bounds__(256) void prep_x(const float* __restrict__ x,
                                              unsigned short* __restrict__ xT) {
    const int l0  = blockIdx.x * 64;
    const int ci0 = blockIdx.y * 64;
    const int b   = blockIdx.z;

    __shared__ float xs[64][68];
    const int tid = threadIdx.x;
    const float* xb = x + ((size_t)b * C_DIM + ci0) * L_DIM;

    for (int idx = tid; idx < 64 * 16; idx += 256) {
        int ci = idx >> 4, lq = idx & 15;
        *(float4*)&xs[ci][lq * 4] = *(const float4*)&xb[(size_t)ci * L_DIM + l0 + lq * 4];
    }
    __syncthreads();

    unsigned short* ob = xT + ((size_t)b * L_DIM + l0) * C_DIM + ci0;
    for (int idx = tid; idx < 64 * 8; idx += 256) {
        int l = idx >> 3, c8 = idx & 7;
        ushort4 r0, r1;
        r0.x = f2h(xs[c8 * 8 + 0][l]); r0.y = f2h(xs[c8 * 8 + 1][l]);
        r0.z = f2h(xs[c8 * 8 + 2][l]); r0.w = f2h(xs[c8 * 8 + 3][l]);
        r1.x = f2h(xs[c8 * 8 + 4][l]); r1.y = f2h(xs[c8 * 8 + 5][l]);
        r1.z = f2h(xs[c8 * 8 + 6][l]); r1.w = f2h(xs[c8 * 8 + 7][l]);
        *(ushort4*)&ob[(size_t)l * C_DIM + c8 * 8] = r0;
        *(ushort4*)&ob[(size_t)l * C_DIM + c8 * 8 + 4] = r1;
    }
}

// ---------------------------------------------------------------------------
// conv_all: out[co,l] = sum_t sum_ci Wh[t][co][ci] * x[ci][l+t-1] via MFMA.
// BK=64 (was 32): halves the barrier-drain count (16 -> 8 iterations).
// LDS: As 27.6 KB + Bs 18.7 KB = 46 KB -> 3 blocks/CU.
// q output (co0==0) is pre-scaled by log2(e) so downstream softmax uses
// native exp2 (v_exp_f32) without the per-element v_mul.
// ---------------------------------------------------------------------------
__global__ __launch_bounds__(256) void conv_all(const unsigned short* __restrict__ Wh,
                                                const unsigned short* __restrict__ xT,
                                                unsigned short* __restrict__ qT,
                                                unsigned short* __restrict__ kT,
                                                unsigned short* __restrict__ vB) {
    const int l0  = blockIdx.x * 128;
    const int co0 = blockIdx.y * 64;
    const int b   = blockIdx.z;

    __shared__ unsigned short As[3][64][72];
    __shared__ unsigned short Bs[130][72];

    const int tid  = threadIdx.x;
    const int lane = tid & 63, w = tid >> 6;
    const int ln15 = lane & 15, quad = lane >> 4;

    const int co_w = (w & 1) * 32;
    const int l_w  = (w >> 1) * 64;

    const unsigned short* xb = xT + (size_t)b * L_DIM * C_DIM;

    f32x4 acc[2][4] = {};

    for (int ci0 = 0; ci0 < C_DIM; ci0 += 64) {
        __syncthreads();
        for (int idx = tid; idx < 1536; idx += 256) {
            int t = idx >> 9, co = (idx >> 3) & 63, c8 = idx & 7;
            *(float4*)&As[t][co][c8 * 8] =
                *(const float4*)&Wh[(((size_t)t * 640) + co0 + co) * C_DIM + ci0 + c8 * 8];
        }
        for (int idx = tid; idx < 1040; idx += 256) {
            int la = idx >> 3, c8 = idx & 7;
            int l = l0 - 1 + la;
            float4 vx = {0.f, 0.f, 0.f, 0.f};
            if (l >= 0 && l < L_DIM)
                vx = *(const float4*)&xb[(size_t)l * C_DIM + ci0 + c8 * 8];
            *(float4*)&Bs[la][c8 * 8] = vx;
        }
        __syncthreads();

#pragma unroll
        for (int t = 0; t < 3; t++) {
#pragma unroll
            for (int ks = 0; ks < 2; ks++) {
                f16x8 a[2], bfr[4];
#pragma unroll
                for (int ct = 0; ct < 2; ct++)
                    a[ct] = *(const f16x8*)&As[t][co_w + ct * 16 + ln15][ks * 32 + quad * 8];
#pragma unroll
                for (int lt = 0; lt < 4; lt++)
                    bfr[lt] = *(const f16x8*)&Bs[l_w + lt * 16 + ln15 + t][ks * 32 + quad * 8];
#pragma unroll
                for (int ct = 0; ct < 2; ct++)
#pragma unroll
                    for (int lt = 0; lt < 4; lt++)
                        acc[ct][lt] = __builtin_amdgcn_mfma_f32_16x16x32_f16(a[ct], bfr[lt], acc[ct][lt], 0, 0, 0);
            }
        }
    }

    if (co0 < 128) {
        const float qs = (co0 == 0) ? LOG2E : 1.0f;   // fold log2(e) into q
        unsigned short* dst = (co0 == 0 ? qT : kT) + (size_t)b * L_DIM * CQ_DIM;
#pragma unroll
        for (int ct = 0; ct < 2; ct++)
#pragma unroll
            for (int lt = 0; lt < 4; lt++) {
                const int l = l0 + l_w + lt * 16 + ln15;
                ushort4 r;
                r.x = f2h(acc[ct][lt][0] * qs); r.y = f2h(acc[ct][lt][1] * qs);
                r.z = f2h(acc[ct][lt][2] * qs); r.w = f2h(acc[ct][lt][3] * qs);
                *(ushort4*)&dst[(size_t)l * CQ_DIM + co_w + ct * 16 + quad * 4] = r;
            }
    } else {
        unsigned short* dst = vB + ((size_t)b * C_DIM + (co0 - 128)) * L_DIM;
#pragma unroll
        for (int ct = 0; ct < 2; ct++)
#pragma unroll
            for (int lt = 0; lt < 4; lt++) {
                const int l = l0 + l_w + lt * 16 + ln15;
#pragma unroll
                for (int r = 0; r < 4; r++) {
                    const int co = co_w + ct * 16 + quad * 4 + r;
                    dst[(size_t)co * L_DIM + l] = f2h(acc[ct][lt][r]);
                }
            }
    }
}

// ---------------------------------------------------------------------------
// stat_k: per-j softmax stats over an i-chunk of 256 (log2 domain: q carries
// log2e, so exp2 is exact-equivalent to exp on unscaled scores).
// Grid (8 ich, 32 jb, 8 b) = 2048 blocks. pm/pl partials to pstat.
// ---------------------------------------------------------------------------
__global__ __launch_bounds__(256) void stat_k(const unsigned short* __restrict__ qT,
                                              const unsigned short* __restrict__ kT,
                                              float* __restrict__ pstat) {
    const int ich = blockIdx.x;
    const int j0  = blockIdx.y * 64;
    const int b   = blockIdx.z;

    __shared__ unsigned short sbuf[64 * 68];

    const int tid = threadIdx.x;
    const int lane = tid & 63, w = tid >> 6;
    const int ln15 = lane & 15, quad = lane >> 4;
    const int sj = w * 16;

    const unsigned short* qb = qT + (size_t)b * L_DIM * CQ_DIM;
    const unsigned short* kb = kT + (size_t)b * L_DIM * CQ_DIM;

    for (int idx = tid; idx < 64 * 8; idx += 256) {
        int r = idx >> 3, c8 = idx & 7;
        *(float4*)&sbuf[r * 68 + c8 * 8] = *(const float4*)&kb[(size_t)(j0 + r) * CQ_DIM + c8 * 8];
    }
    __syncthreads();
    f16x8 kfr[2];
#pragma unroll
    for (int cc = 0; cc < 2; cc++)
        kfr[cc] = *(const f16x8*)&sbuf[(sj + ln15) * 68 + cc * 32 + quad * 8];

    float m_run = -1e30f, l_run = 0.f;

    for (int t = 0; t < 4; t++) {
        const int i0 = ich * 256 + t * 64;
        __syncthreads();
        for (int idx = tid; idx < 64 * 8; idx += 256) {
            int r = idx >> 3, c8 = idx & 7;
            *(float4*)&sbuf[r * 68 + c8 * 8] = *(const float4*)&qb[(size_t)(i0 + r) * CQ_DIM + c8 * 8];
        }
        __syncthreads();

        f32x4 sacc[4] = {};
#pragma unroll
        for (int cc = 0; cc < 2; cc++) {
#pragma unroll
            for (int it = 0; it < 4; it++) {
                const f16x8 afr = *(const f16x8*)&sbuf[(it * 16 + ln15) * 68 + cc * 32 + quad * 8];
                sacc[it] = __builtin_amdgcn_mfma_f32_16x16x32_f16(afr, kfr[cc], sacc[it], 0, 0, 0);
            }
        }

        float bm = -1e30f;
#pragma unroll
        for (int it = 0; it < 4; it++)
#pragma unroll
            for (int r = 0; r < 4; r++)
                bm = fmaxf(bm, sacc[it][r]);
        bm = fmaxf(bm, __shfl_xor(bm, 16, 64));
        bm = fmaxf(bm, __shfl_xor(bm, 32, 64));
        const float m_new = fmaxf(m_run, bm);
        const float alpha = exp2f(m_run - m_new);

        float lsum = 0.f;
#pragma unroll
        for (int it = 0; it < 4; it++) {
            float p0 = exp2f(sacc[it][0] - m_new);
            float p1 = exp2f(sacc[it][1] - m_new);
            float p2 = exp2f(sacc[it][2] - m_new);
            float p3 = exp2f(sacc[it][3] - m_new);
            lsum += (p0 + p1) + (p2 + p3);
        }
        lsum += __shfl_xor(lsum, 16, 64);
        lsum += __shfl_xor(lsum, 32, 64);
        l_run = l_run * alpha + lsum;
        m_run = m_new;
    }

    if (quad == 0) {
        const int j = j0 + sj + ln15;
        float* pm = pstat;
        float* pl = pstat + 8 * 8 * 2048;
        pm[((size_t)ich * 8 + b) * 2048 + j] = m_run;
        pl[((size_t)ich * 8 + b) * 2048 + j] = l_run;
    }
}

// ---------------------------------------------------------------------------
// pv2: dependency-free PV with precomputed exact (m_j, l_j), log2 domain.
// Block 64j x 128co, 4 waves, grid (32, 4, 8) = 1024 blocks, ~35 KB LDS.
// Wave-owned-j: wave w owns j-group w*16 end-to-end (scores, exp2, P rows,
// O[128co x 16j]). P never crosses waves -> only 2 barriers/iter; after the
// stage barrier each wave's score->exp2->PV chain runs decoupled (phase skew
// hides VALU under other waves' MFMA; setprio arbitrates).
// NO register prefetch: rounds 1/5 proved demand >~85 VGPR trips the
// allocator's 64-tier clamp and spills (~450 MB scratch). Demand here ~75.
// ---------------------------------------------------------------------------
__global__ __launch_bounds__(256) void pv2(const unsigned short* __restrict__ qT,
                                           const unsigned short* __restrict__ kT,
                                           const unsigned short* __restrict__ vB,
                                           const float* __restrict__ pstat,
                                           const float* __restrict__ gamma,
                                           float* __restrict__ out) {
    const int j0  = blockIdx.x * 64;
    const int co0 = blockIdx.y * 128;
    const int b   = blockIdx.z;

    __shared__ unsigned short pps[64 * 68];   // init: kT stage; loop: P rows (wave-private)
    __shared__ unsigned short qTs[64 * 68];   // [i][c]
    __shared__ unsigned short vvs[128 * 68];  // [co][i]
    __shared__ float mj_s[64];
    __shared__ float il_s[64];

    const int tid = threadIdx.x;
    const int lane = tid & 63, w = tid >> 6;
    const int ln15 = lane & 15, quad = lane >> 4;

    const unsigned short* qb = qT + (size_t)b * L_DIM * CQ_DIM;
    const unsigned short* kb = kT + (size_t)b * L_DIM * CQ_DIM;
    const unsigned short* vb = vB + (size_t)b * C_DIM * L_DIM;

    const int sj = w * 16;   // wave's j group (owned end-to-end)

    // ---- merge per-chunk stats (log2 domain) ----
    if (tid < 64) {
        const int j = j0 + tid;
        const float* pm = pstat;
        const float* pl = pstat + 8 * 8 * 2048;
        float m = -1e30f;
        float pmv[8];
#pragma unroll
        for (int c = 0; c < 8; c++) {
            pmv[c] = pm[((size_t)c * 8 + b) * 2048 + j];
            m = fmaxf(m, pmv[c]);
        }
        float l = 0.f;
#pragma unroll
        for (int c = 0; c < 8; c++)
            l = fmaf(pl[((size_t)c * 8 + b) * 2048 + j], exp2f(pmv[c] - m), l);
        mj_s[tid] = m;
        il_s[tid] = gamma[0] / l;
    }

    // ---- stage kT once, hoist this wave's K-fragments ----
    for (int idx = tid; idx < 64 * 8; idx += 256) {
        int r = idx >> 3, c8 = idx & 7;
        *(float4*)&pps[r * 68 + c8 * 8] = *(const float4*)&kb[(size_t)(j0 + r) * CQ_DIM + c8 * 8];
    }
    __syncthreads();
    f16x8 kfr[2];
#pragma unroll
    for (int cc = 0; cc < 2; cc++)
        kfr[cc] = *(const f16x8*)&pps[(sj + ln15) * 68 + cc * 32 + quad * 8];
    const float m_lane   = mj_s[sj + ln15];
    const float inv_lane = il_s[sj + ln15];

    f32x4 oacc[8] = {};   // O[co-tile a][j = sj+ln15], a covers 128 co

    for (int i0 = 0; i0 < L_DIM; i0 += 64) {
        __syncthreads();   // all waves done reading qTs/vvs/pps of prior iter
        for (int idx = tid; idx < 64 * 8; idx += 256) {
            int r = idx >> 3, c8 = idx & 7;
            *(float4*)&qTs[r * 68 + c8 * 8] = *(const float4*)&qb[(size_t)(i0 + r) * CQ_DIM + c8 * 8];
        }
        for (int idx = tid; idx < 128 * 8; idx += 256) {
            int r = idx >> 3, c8 = idx & 7;
            *(float4*)&vvs[r * 68 + c8 * 8] = *(const float4*)&vb[(size_t)(co0 + r) * L_DIM + i0 + c8 * 8];
        }
        __syncthreads();

        // scores: S'[64i x 16j] (log2 domain) for this wave's j group
        f32x4 sacc[4] = {};
        __builtin_amdgcn_s_setprio(1);
#pragma unroll
        for (int cc = 0; cc < 2; cc++) {
#pragma unroll
            for (int it = 0; it < 4; it++) {
                const f16x8 afr = *(const f16x8*)&qTs[(it * 16 + ln15) * 68 + cc * 32 + quad * 8];
                sacc[it] = __builtin_amdgcn_mfma_f32_16x16x32_f16(afr, kfr[cc], sacc[it], 0, 0, 0);
            }
        }
        __builtin_amdgcn_s_setprio(0);

        // p = exp2(S' - m'_j), written to this wave's own pps rows
        const int j = sj + ln15;
#pragma unroll
        for (int it = 0; it < 4; it++) {
            float p0 = exp2f(sacc[it][0] - m_lane);
            float p1 = exp2f(sacc[it][1] - m_lane);
            float p2 = exp2f(sacc[it][2] - m_lane);
            float p3 = exp2f(sacc[it][3] - m_lane);
            uint2 u;
            u.x = p2u(p0, p1);
            u.y = p2u(p2, p3);
            *(uint2*)&pps[j * 68 + it * 16 + quad * 4] = u;
        }
        // no barrier: wave reads back only its own rows (lgkmcnt orders)

        // PV: oacc[a] += V[128co x 64i] * P[64i x 16j(own)]
        __builtin_amdgcn_s_setprio(1);
#pragma unroll
        for (int ks = 0; ks < 2; ks++) {
            const f16x8 bfr = *(const f16x8*)&pps[(sj + ln15) * 68 + ks * 32 + quad * 8];
#pragma unroll
            for (int a = 0; a < 8; a++) {
                const f16x8 afr = *(const f16x8*)&vvs[(a * 16 + ln15) * 68 + ks * 32 + quad * 8];
                oacc[a] = __builtin_amdgcn_mfma_f32_16x16x32_f16(afr, bfr, oacc[a], 0, 0, 0);
            }
        }
        __builtin_amdgcn_s_setprio(0);
    }

    // epilogue: out = oacc * (gamma / l_j), col j = j0 + sj + ln15
#pragma unroll
    for (int a = 0; a < 8; a++)
#pragma unroll
        for (int r = 0; r < 4; r++) {
            const int co = co0 + a * 16 + quad * 4 + r;
            out[((size_t)b * C_DIM + co) * L_DIM + j0 + sj + ln15] = oacc[a][r] * inv_lane;
        }
}

// ---------------------------------------------------------------------------
extern "C" void kernel_launch(void* const* d_in, const int* in_sizes, int n_in,
                              void* d_out, int out_size, void* d_ws, size_t ws_size,
                              hipStream_t stream) {
    const float* x     = (const float*)d_in[0];
    const float* Wq    = (const float*)d_in[1];
    const float* Wk    = (const float*)d_in[2];
    const float* Wv    = (const float*)d_in[3];
    const float* gamma = (const float*)d_in[4];
    float* out = (float*)d_out;

    unsigned short* ws_h = (unsigned short*)d_ws;
    unsigned short* qT = ws_h;                        // 8*2048*64   = 1,048,576
    unsigned short* kT = qT + 1048576;
    unsigned short* vB = kT + 1048576;                // 8*512*2048  = 8,388,608
    unsigned short* xT = vB + 8388608;                // 8*2048*512  = 8,388,608
    unsigned short* Wh = xT + 8388608;                // 3*640*512   = 983,040
    // stats reuse the xT region (dead after conv_all): 2 * 8*8*2048 floats = 1 MB
    float* pstat = (float*)xT;

    prep_w  <<<3840, 256, 0, stream>>>(Wq, Wk, Wv, Wh);
    prep_x  <<<dim3(32, 8, 8), 256, 0, stream>>>(x, xT);
    conv_all<<<dim3(16, 10, 8), 256, 0, stream>>>(Wh, xT, qT, kT, vB);
    stat_k  <<<dim3(8, 32, 8), 256, 0, stream>>>(qT, kT, pstat);
    pv2     <<<dim3(32, 4, 8), 256, 0, stream>>>(qT, kT, vB, pstat, gamma, out);
}